// Round 1
// baseline (642.538 us; speedup 1.0000x reference)
//
#include <hip/hip_runtime.h>

#define NN 100000
#define NE 1600000
#define NF 128
#define NH 64
#define NK 20

static constexpr float ALPHA = 0.2f;

// ---- workspace layout (aligned to 256B) ----
constexpr size_t alup(size_t x) { return (x + 255) & ~size_t(255); }
constexpr size_t O_FLAG = 0;                                // 4 B
constexpr size_t O_DINV = 256;                              // NN f32 (deg then dinv)
constexpr size_t O_SRC  = alup(O_DINV + size_t(NN) * 4);    // NE i32
constexpr size_t O_DST  = alup(O_SRC + size_t(NE) * 4);     // NE i32
constexpr size_t O_SUP  = alup(O_DST + size_t(NE) * 4);     // NN*NH f32  (~25.6 MB)
// total ≈ 38.8 MB

// Detect whether edge_index is int64 or int32 on device.
// int64 data: first 1024 values all in [0, NN). int32 data read as int64:
// value = lo + hi*2^32 with hi a random node id -> out of range almost surely.
__global__ void k_detect(const void* ei, int* flag) {
  const long long* p = (const long long*)ei;
  int is64 = 1;
  for (int i = 0; i < 1024; ++i) {
    long long v = p[i];
    if (v < 0 || v >= NN) { is64 = 0; break; }
  }
  *flag = is64;
}

__global__ __launch_bounds__(256) void k_convert(const void* ei, const int* __restrict__ flag,
                                                 int* __restrict__ src, int* __restrict__ dst) {
  int e = blockIdx.x * 256 + threadIdx.x;
  if (e >= NE) return;
  if (*flag) {
    const long long* p = (const long long*)ei;
    src[e] = (int)p[e];
    dst[e] = (int)p[NE + e];
  } else {
    const int* p = (const int*)ei;
    src[e] = p[e];
    dst[e] = p[NE + e];
  }
}

__global__ __launch_bounds__(256) void k_deg_init(float* deg) {
  int i = blockIdx.x * 256 + threadIdx.x;
  if (i < NN) deg[i] = 1.0f;  // self-loop weight
}

__global__ __launch_bounds__(256) void k_deg_acc(const int* __restrict__ dst,
                                                 const float* __restrict__ w, float* deg) {
  int e = blockIdx.x * 256 + threadIdx.x;
  if (e < NE) atomicAdd(&deg[dst[e]], w[e]);
}

__global__ __launch_bounds__(256) void k_dinv(float* deg) {
  int i = blockIdx.x * 256 + threadIdx.x;
  if (i < NN) { float d = deg[i]; deg[i] = d > 0.f ? rsqrtf(d) : 0.f; }
}

// support = x @ W ; W (128x64 f32 = 32KB) staged in LDS, 16 threads per row,
// each thread owns 4 consecutive output columns (float4 LDS reads, 2-way = free).
__global__ __launch_bounds__(256) void k_gemm(const float* __restrict__ x,
                                              const float* __restrict__ W,
                                              float* __restrict__ sup) {
  __shared__ float4 Wl[NF * NH / 4];
  const float4* Wg = (const float4*)W;
  for (int i = threadIdx.x; i < NF * NH / 4; i += 256) Wl[i] = Wg[i];
  __syncthreads();
  int lane16 = threadIdx.x & 15;   // column group: cols [lane16*4, lane16*4+4)
  int rowin  = threadIdx.x >> 4;   // 0..15
  const float4* x4 = (const float4*)x;
  float4* s4 = (float4*)sup;
  int rowbase = blockIdx.x * 128;
  for (int r0 = 0; r0 < 128; r0 += 16) {
    int r = rowbase + r0 + rowin;
    if (r >= NN) return;
    float4 acc = make_float4(0.f, 0.f, 0.f, 0.f);
#pragma unroll 8
    for (int kk = 0; kk < NF / 4; ++kk) {
      float4 xv = x4[r * (NF / 4) + kk];
      float4 w0 = Wl[(4 * kk + 0) * 16 + lane16];
      float4 w1 = Wl[(4 * kk + 1) * 16 + lane16];
      float4 w2 = Wl[(4 * kk + 2) * 16 + lane16];
      float4 w3 = Wl[(4 * kk + 3) * 16 + lane16];
      acc.x += xv.x * w0.x + xv.y * w1.x + xv.z * w2.x + xv.w * w3.x;
      acc.y += xv.x * w0.y + xv.y * w1.y + xv.z * w2.y + xv.w * w3.y;
      acc.z += xv.x * w0.z + xv.y * w1.z + xv.z * w2.z + xv.w * w3.z;
      acc.w += xv.x * w0.w + xv.y * w1.w + xv.z * w2.w + xv.w * w3.w;
    }
    s4[r * (NH / 4) + lane16] = acc;
  }
}

// z[i][f] = dinv[i]^2 * support[i][f] + b[f]   (self-loop term + bias)
__global__ __launch_bounds__(256) void k_zinit(const float* __restrict__ sup,
                                               const float* __restrict__ dinv,
                                               const float* __restrict__ b,
                                               float* __restrict__ z) {
  int i = blockIdx.x * 256 + threadIdx.x;
  if (i >= NN * NH) return;
  int row = i >> 6, f = i & 63;
  float di = dinv[row];
  z[i] = di * di * sup[i] + b[f];
}

// One wave per edge; lane = feature. Per-edge scalars are wave-uniform
// broadcast loads. Gather + 64 coalesced f32 atomics per edge.
__global__ __launch_bounds__(256) void k_scatter(const int* __restrict__ src,
                                                 const int* __restrict__ dst,
                                                 const float* __restrict__ w,
                                                 const float* __restrict__ dinv,
                                                 const float* __restrict__ sup,
                                                 float* __restrict__ z) {
  int t = blockIdx.x * 256 + threadIdx.x;
  int e = t >> 6;
  if (e >= NE) return;
  int f = t & 63;
  int s = src[e], d = dst[e];
  float norm = dinv[s] * w[e] * dinv[d];
  atomicAdd(&z[d * NH + f], norm * sup[s * NH + f]);
}

// Student-t head: one wave per node, mu in LDS, butterfly reductions.
__global__ __launch_bounds__(256) void k_q(const float* __restrict__ z,
                                           const float* __restrict__ mu,
                                           float* __restrict__ q) {
  __shared__ float mul[NK * NH];
  for (int i = threadIdx.x; i < NK * NH; i += 256) mul[i] = mu[i];
  __syncthreads();
  int wid  = (blockIdx.x * 256 + threadIdx.x) >> 6;
  int lane = threadIdx.x & 63;
  if (wid >= NN) return;
  float zv = z[wid * NH + lane];
  float d2m = 0.f;
#pragma unroll
  for (int k = 0; k < NK; ++k) {
    float diff = zv - mul[k * NH + lane];
    float s = diff * diff;
    for (int off = 32; off; off >>= 1) s += __shfl_xor(s, off, 64);
    if (lane == k) d2m = s;  // lane k keeps cluster k's distance
  }
  float qv = 0.f;
  if (lane < NK) {
    float tq = 1.0f / (1.0f + d2m * (1.0f / ALPHA) + 1e-8f);
    qv = 0.5f * powf(tq, ALPHA + 1.0f);
  }
  float ssum = qv;
  for (int off = 32; off; off >>= 1) ssum += __shfl_xor(ssum, off, 64);
  if (lane < NK) q[wid * NK + lane] = qv / ssum;
}

extern "C" void kernel_launch(void* const* d_in, const int* in_sizes, int n_in,
                              void* d_out, int out_size, void* d_ws, size_t ws_size,
                              hipStream_t stream) {
  const float* x  = (const float*)d_in[0];
  const void*  ei = d_in[1];
  const float* w  = (const float*)d_in[2];
  const float* W  = (const float*)d_in[3];
  const float* b  = (const float*)d_in[4];
  const float* mu = (const float*)d_in[5];

  char* ws = (char*)d_ws;
  int*   flag = (int*)(ws + O_FLAG);
  float* dinv = (float*)(ws + O_DINV);
  int*   src  = (int*)(ws + O_SRC);
  int*   dst  = (int*)(ws + O_DST);
  float* sup  = (float*)(ws + O_SUP);

  float* z = (float*)d_out;
  float* q = (float*)d_out + (size_t)NN * NH;

  hipLaunchKernelGGL(k_detect,   dim3(1),                dim3(1),   0, stream, ei, flag);
  hipLaunchKernelGGL(k_convert,  dim3((NE + 255) / 256), dim3(256), 0, stream, ei, flag, src, dst);
  hipLaunchKernelGGL(k_deg_init, dim3((NN + 255) / 256), dim3(256), 0, stream, dinv);
  hipLaunchKernelGGL(k_deg_acc,  dim3((NE + 255) / 256), dim3(256), 0, stream, dst, w, dinv);
  hipLaunchKernelGGL(k_dinv,     dim3((NN + 255) / 256), dim3(256), 0, stream, dinv);
  hipLaunchKernelGGL(k_gemm,     dim3((NN + 127) / 128), dim3(256), 0, stream, x, W, sup);
  hipLaunchKernelGGL(k_zinit,    dim3((NN * NH) / 256),  dim3(256), 0, stream, sup, dinv, b, z);
  hipLaunchKernelGGL(k_scatter,  dim3((NE * 64) / 256),  dim3(256), 0, stream, src, dst, w, dinv, sup, z);
  hipLaunchKernelGGL(k_q,        dim3((NN * 64) / 256),  dim3(256), 0, stream, z, mu, q);
}

// Round 2
// 516.748 us; speedup vs baseline: 1.2434x; 1.2434x over previous
//
#include <hip/hip_runtime.h>

#define NN 100000
#define NE 1600000
#define NF 128
#define NH 64
#define NK 20
#define CH 2048
#define NCH ((NN + CH - 1) / CH)   // 49

static constexpr float ALPHA = 0.2f;

// ---- workspace layout (aligned to 256B) ----
constexpr size_t alup(size_t x) { return (x + 255) & ~size_t(255); }
constexpr size_t O_FLAG  = 0;                                  // 4 B
constexpr size_t O_DEG   = 256;                                // NN f32 (deg -> dinv in place)
constexpr size_t O_HIST  = alup(O_DEG  + size_t(NN) * 4);      // NN i32
constexpr size_t O_OFF   = alup(O_HIST + size_t(NN) * 4);      // (NN+1) i32
constexpr size_t O_CUR   = alup(O_OFF  + size_t(NN + 1) * 4);  // NN i32
constexpr size_t O_CHS   = alup(O_CUR  + size_t(NN) * 4);      // 64 i32
constexpr size_t O_CHO   = alup(O_CHS  + 64 * 4);              // 64 i32
constexpr size_t O_ESRC  = alup(O_CHO  + 64 * 4);              // NE+64 i32 (sorted src)
constexpr size_t O_ENORM = alup(O_ESRC + size_t(NE + 64) * 4); // NE+64 f32 (sorted norm)
constexpr size_t O_SUP   = alup(O_ENORM + size_t(NE + 64) * 4);// NN*NH f32 (~25.6 MB)
// total ~ 41 MB

// edge_index dtype probe: int64 data has first 1024 values all in [0,NN).
__global__ void k_detect(const void* ei, int* flag) {
  const long long* p = (const long long*)ei;
  int is64 = 1;
  for (int i = 0; i < 1024; ++i) {
    long long v = p[i];
    if (v < 0 || v >= NN) { is64 = 0; break; }
  }
  *flag = is64;
}

__device__ __forceinline__ void load_edge(const void* ei, int is64, int e, int& s, int& d) {
  if (is64) {
    const long long* p = (const long long*)ei;
    s = (int)p[e]; d = (int)p[NE + e];
  } else {
    const int* p = (const int*)ei;
    s = p[e]; d = p[NE + e];
  }
}

__global__ __launch_bounds__(256) void k_init(float* deg, int* hist) {
  int i = blockIdx.x * 256 + threadIdx.x;
  if (i < NN) { deg[i] = 0.f; hist[i] = 0; }
}

// per-edge: deg[dst] += w, hist[dst] += 1
__global__ __launch_bounds__(256) void k_hist(const void* ei, const int* __restrict__ flag,
                                              const float* __restrict__ w,
                                              float* deg, int* hist) {
  int e = blockIdx.x * 256 + threadIdx.x;
  if (e >= NE) return;
  int s, d; load_edge(ei, *flag, e, s, d);
  atomicAdd(&deg[d], w[e]);
  atomicAdd(&hist[d], 1);
}

__global__ __launch_bounds__(256) void k_dinv(float* deg) {
  int i = blockIdx.x * 256 + threadIdx.x;
  if (i < NN) deg[i] = rsqrtf(deg[i] + 1.0f);   // +1 = self-loop weight; always > 0
}

// ---- 3-kernel exclusive scan of hist -> off (and cursor copy) ----
__global__ __launch_bounds__(256) void k_chsum(const int* __restrict__ hist, int* chs) {
  int b = blockIdx.x, t = threadIdx.x;
  int base = b * CH + t * 8;
  int s = 0;
#pragma unroll
  for (int k = 0; k < 8; ++k) { int i = base + k; if (i < NN) s += hist[i]; }
  for (int o = 32; o; o >>= 1) s += __shfl_xor(s, o, 64);
  __shared__ int wt[4];
  if ((t & 63) == 0) wt[t >> 6] = s;
  __syncthreads();
  if (t == 0) chs[b] = wt[0] + wt[1] + wt[2] + wt[3];
}

__global__ void k_scantop(const int* __restrict__ chs, int* cho) {
  int lane = threadIdx.x;  // 64 threads
  int v = lane < NCH ? chs[lane] : 0;
  int inc = v;
  for (int d = 1; d < 64; d <<= 1) { int t = __shfl_up(inc, d, 64); if (lane >= d) inc += t; }
  if (lane < NCH) cho[lane] = inc - v;  // exclusive
}

__global__ __launch_bounds__(256) void k_scanapply(const int* __restrict__ hist,
                                                   const int* __restrict__ cho,
                                                   int* off, int* cursor) {
  int b = blockIdx.x, t = threadIdx.x;
  int base = b * CH + t * 8;
  int e[8]; int s = 0;
#pragma unroll
  for (int k = 0; k < 8; ++k) { int i = base + k; e[k] = (i < NN) ? hist[i] : 0; s += e[k]; }
  int lane = t & 63, wv = t >> 6;
  int inc = s;
  for (int d = 1; d < 64; d <<= 1) { int tt = __shfl_up(inc, d, 64); if (lane >= d) inc += tt; }
  __shared__ int wtot[4];
  if (lane == 63) wtot[wv] = inc;
  __syncthreads();
  int wbase = 0;
#pragma unroll
  for (int k = 0; k < 4; ++k) if (k < wv) wbase += wtot[k];
  int run = wbase + (inc - s) + cho[b];
#pragma unroll
  for (int k = 0; k < 8; ++k) {
    int i = base + k;
    if (i < NN) { off[i] = run; cursor[i] = run; }
    run += e[k];
  }
  if (b == 0 && t == 0) off[NN] = NE;
}

// bucket-scatter edges into dst-sorted order; norm precomputed
__global__ __launch_bounds__(256) void k_sortedges(const void* ei, const int* __restrict__ flag,
                                                   const float* __restrict__ w,
                                                   const float* __restrict__ dinv,
                                                   int* cursor,
                                                   int* __restrict__ esrc,
                                                   float* __restrict__ enorm) {
  int e = blockIdx.x * 256 + threadIdx.x;
  if (e >= NE) return;
  int s, d; load_edge(ei, *flag, e, s, d);
  float nr = dinv[s] * w[e] * dinv[d];
  int pos = atomicAdd(&cursor[d], 1);
  esrc[pos] = s;
  enorm[pos] = nr;
}

// support = x @ W ; W (128x64 f32 = 32KB) staged in LDS as float4 blocks.
__global__ __launch_bounds__(256) void k_gemm(const float* __restrict__ x,
                                              const float* __restrict__ W,
                                              float* __restrict__ sup) {
  __shared__ float4 Wl[NF * NH / 4];
  const float4* Wg = (const float4*)W;
  for (int i = threadIdx.x; i < NF * NH / 4; i += 256) Wl[i] = Wg[i];
  __syncthreads();
  int lane16 = threadIdx.x & 15;
  int rowin  = threadIdx.x >> 4;
  const float4* x4 = (const float4*)x;
  float4* s4 = (float4*)sup;
  int rowbase = blockIdx.x * 128;
  for (int r0 = 0; r0 < 128; r0 += 16) {
    int r = rowbase + r0 + rowin;
    if (r >= NN) return;
    float4 acc = make_float4(0.f, 0.f, 0.f, 0.f);
#pragma unroll 8
    for (int kk = 0; kk < NF / 4; ++kk) {
      float4 xv = x4[r * (NF / 4) + kk];
      float4 w0 = Wl[(4 * kk + 0) * 16 + lane16];
      float4 w1 = Wl[(4 * kk + 1) * 16 + lane16];
      float4 w2 = Wl[(4 * kk + 2) * 16 + lane16];
      float4 w3 = Wl[(4 * kk + 3) * 16 + lane16];
      acc.x += xv.x * w0.x + xv.y * w1.x + xv.z * w2.x + xv.w * w3.x;
      acc.y += xv.x * w0.y + xv.y * w1.y + xv.z * w2.y + xv.w * w3.y;
      acc.z += xv.x * w0.z + xv.y * w1.z + xv.z * w2.z + xv.w * w3.z;
      acc.w += xv.x * w0.w + xv.y * w1.w + xv.z * w2.w + xv.w * w3.w;
    }
    s4[r * (NH / 4) + lane16] = acc;
  }
}

// One wave per node: segment-reduce incoming edges + self-loop + bias -> z,
// then Student-t soft assignment -> q. No atomics.
__global__ __launch_bounds__(256) void k_agg_q(const int* __restrict__ esrc,
                                               const float* __restrict__ enorm,
                                               const int* __restrict__ off,
                                               const float* __restrict__ dinv,
                                               const float* __restrict__ sup,
                                               const float* __restrict__ b,
                                               const float* __restrict__ mu,
                                               float* __restrict__ z,
                                               float* __restrict__ q) {
  __shared__ float mul[NK * NH];
  for (int i = threadIdx.x; i < NK * NH; i += 256) mul[i] = mu[i];
  __syncthreads();
  int wid  = (blockIdx.x * 256 + threadIdx.x) >> 6;  // node
  int lane = threadIdx.x & 63;                       // feature
  if (wid >= NN) return;

  int start = off[wid], end = off[wid + 1];
  float di = dinv[wid];
  float acc = di * di * sup[wid * NH + lane] + b[lane];

  for (int j0 = start; j0 < end; j0 += 64) {
    int idx = j0 + lane;
    int s = 0; float nr = 0.f;
    if (idx < end) { s = esrc[idx]; nr = enorm[idx]; }
    int cnt = min(end - j0, 64);
    for (int j = 0; j < cnt; ++j) {
      int   ss = __shfl(s, j, 64);
      float nw = __shfl(nr, j, 64);
      acc += nw * sup[ss * NH + lane];
    }
  }
  z[wid * NH + lane] = acc;

  // Student-t head
  float d2m = 0.f;
#pragma unroll
  for (int k = 0; k < NK; ++k) {
    float diff = acc - mul[k * NH + lane];
    float s2 = diff * diff;
    for (int o = 32; o; o >>= 1) s2 += __shfl_xor(s2, o, 64);
    if (lane == k) d2m = s2;
  }
  float qv = 0.f;
  if (lane < NK) {
    float tq = 1.0f / (1.0f + d2m * (1.0f / ALPHA) + 1e-8f);
    qv = 0.5f * powf(tq, ALPHA + 1.0f);
  }
  float ssum = qv;
  for (int o = 32; o; o >>= 1) ssum += __shfl_xor(ssum, o, 64);
  if (lane < NK) q[wid * NK + lane] = qv / ssum;
}

extern "C" void kernel_launch(void* const* d_in, const int* in_sizes, int n_in,
                              void* d_out, int out_size, void* d_ws, size_t ws_size,
                              hipStream_t stream) {
  const float* x  = (const float*)d_in[0];
  const void*  ei = d_in[1];
  const float* w  = (const float*)d_in[2];
  const float* W  = (const float*)d_in[3];
  const float* b  = (const float*)d_in[4];
  const float* mu = (const float*)d_in[5];

  char* ws = (char*)d_ws;
  int*   flag   = (int*)(ws + O_FLAG);
  float* dinv   = (float*)(ws + O_DEG);
  int*   hist   = (int*)(ws + O_HIST);
  int*   off    = (int*)(ws + O_OFF);
  int*   cursor = (int*)(ws + O_CUR);
  int*   chs    = (int*)(ws + O_CHS);
  int*   cho    = (int*)(ws + O_CHO);
  int*   esrc   = (int*)(ws + O_ESRC);
  float* enorm  = (float*)(ws + O_ENORM);
  float* sup    = (float*)(ws + O_SUP);

  float* z = (float*)d_out;
  float* q = (float*)d_out + (size_t)NN * NH;

  hipLaunchKernelGGL(k_detect,    dim3(1),                 dim3(1),   0, stream, ei, flag);
  hipLaunchKernelGGL(k_init,      dim3((NN + 255) / 256),  dim3(256), 0, stream, dinv, hist);
  hipLaunchKernelGGL(k_hist,      dim3((NE + 255) / 256),  dim3(256), 0, stream, ei, flag, w, dinv, hist);
  hipLaunchKernelGGL(k_dinv,      dim3((NN + 255) / 256),  dim3(256), 0, stream, dinv);
  hipLaunchKernelGGL(k_chsum,     dim3(NCH),               dim3(256), 0, stream, hist, chs);
  hipLaunchKernelGGL(k_scantop,   dim3(1),                 dim3(64),  0, stream, chs, cho);
  hipLaunchKernelGGL(k_scanapply, dim3(NCH),               dim3(256), 0, stream, hist, cho, off, cursor);
  hipLaunchKernelGGL(k_sortedges, dim3((NE + 255) / 256),  dim3(256), 0, stream, ei, flag, w, dinv, cursor, esrc, enorm);
  hipLaunchKernelGGL(k_gemm,      dim3((NN + 127) / 128),  dim3(256), 0, stream, x, W, sup);
  hipLaunchKernelGGL(k_agg_q,     dim3((NN * 64) / 256),   dim3(256), 0, stream, esrc, enorm, off, dinv, sup, b, mu, z, q);
}

// Round 3
// 476.962 us; speedup vs baseline: 1.3471x; 1.0834x over previous
//
#include <hip/hip_runtime.h>

#define NN 100000
#define NE 1600000
#define NF 128
#define NH 64
#define NK 20
#define CH 2048
#define NCH ((NN + CH - 1) / CH)   // 49

static constexpr float ALPHA = 0.2f;

// ---- workspace layout (aligned to 256B) ----
constexpr size_t alup(size_t x) { return (x + 255) & ~size_t(255); }
constexpr size_t O_FLAG  = 0;                                  // 4 B
constexpr size_t O_DEG   = 256;                                // NN f32 (deg -> dinv in place)
constexpr size_t O_HIST  = alup(O_DEG  + size_t(NN) * 4);      // NN i32
constexpr size_t O_OFF   = alup(O_HIST + size_t(NN) * 4);      // (NN+1) i32
constexpr size_t O_CUR   = alup(O_OFF  + size_t(NN + 1) * 4);  // NN i32
constexpr size_t O_CHS   = alup(O_CUR  + size_t(NN) * 4);      // 64 i32
constexpr size_t O_CHO   = alup(O_CHS  + 64 * 4);              // 64 i32
constexpr size_t O_EPAIR = alup(O_CHO  + 64 * 4);              // (NE+64) int2 (src, w-bits), dst-sorted
constexpr size_t O_SUP   = alup(O_EPAIR + size_t(NE + 64) * 8);// NN*NH f32 (~25.6 MB) = dinv-scaled x@W
// total ~ 41 MB

// edge_index dtype probe: int64 data has first 1024 values all in [0,NN).
__global__ __launch_bounds__(256) void k_detect(const void* ei, int* flag) {
  __shared__ int bad;
  if (threadIdx.x == 0) bad = 0;
  __syncthreads();
  const long long* p = (const long long*)ei;
  int ok = 1;
#pragma unroll
  for (int k = 0; k < 4; ++k) {
    long long v = p[threadIdx.x * 4 + k];
    if (v < 0 || v >= NN) ok = 0;
  }
  if (!ok) atomicOr(&bad, 1);
  __syncthreads();
  if (threadIdx.x == 0) *flag = bad ? 0 : 1;
}

__device__ __forceinline__ void load_edge(const void* ei, int is64, int e, int& s, int& d) {
  if (is64) {
    const long long* p = (const long long*)ei;
    s = (int)p[e]; d = (int)p[NE + e];
  } else {
    const int* p = (const int*)ei;
    s = p[e]; d = p[NE + e];
  }
}

__global__ __launch_bounds__(256) void k_init(float* deg, int* hist) {
  int i = blockIdx.x * 256 + threadIdx.x;
  if (i < NN) { deg[i] = 0.f; hist[i] = 0; }
}

// per-edge: deg[dst] += w, hist[dst] += 1
__global__ __launch_bounds__(256) void k_hist(const void* ei, const int* __restrict__ flag,
                                              const float* __restrict__ w,
                                              float* deg, int* hist) {
  int e = blockIdx.x * 256 + threadIdx.x;
  if (e >= NE) return;
  int s, d; load_edge(ei, *flag, e, s, d);
  atomicAdd(&deg[d], w[e]);
  atomicAdd(&hist[d], 1);
}

// per-chunk sums of hist (for top-level scan) + deg -> dinv in place (fused)
__global__ __launch_bounds__(256) void k_chsum(const int* __restrict__ hist, int* chs,
                                               float* deg) {
  int b = blockIdx.x, t = threadIdx.x;
  int base = b * CH + t * 8;
  int s = 0;
#pragma unroll
  for (int k = 0; k < 8; ++k) {
    int i = base + k;
    if (i < NN) {
      s += hist[i];
      deg[i] = rsqrtf(deg[i] + 1.0f);  // +1 = self-loop weight; always > 0
    }
  }
  for (int o = 32; o; o >>= 1) s += __shfl_xor(s, o, 64);
  __shared__ int wt[4];
  if ((t & 63) == 0) wt[t >> 6] = s;
  __syncthreads();
  if (t == 0) chs[b] = wt[0] + wt[1] + wt[2] + wt[3];
}

__global__ void k_scantop(const int* __restrict__ chs, int* cho) {
  int lane = threadIdx.x;  // 64 threads
  int v = lane < NCH ? chs[lane] : 0;
  int inc = v;
  for (int d = 1; d < 64; d <<= 1) { int t = __shfl_up(inc, d, 64); if (lane >= d) inc += t; }
  if (lane < NCH) cho[lane] = inc - v;  // exclusive
}

__global__ __launch_bounds__(256) void k_scanapply(const int* __restrict__ hist,
                                                   const int* __restrict__ cho,
                                                   int* off, int* cursor) {
  int b = blockIdx.x, t = threadIdx.x;
  int base = b * CH + t * 8;
  int e[8]; int s = 0;
#pragma unroll
  for (int k = 0; k < 8; ++k) { int i = base + k; e[k] = (i < NN) ? hist[i] : 0; s += e[k]; }
  int lane = t & 63, wv = t >> 6;
  int inc = s;
  for (int d = 1; d < 64; d <<= 1) { int tt = __shfl_up(inc, d, 64); if (lane >= d) inc += tt; }
  __shared__ int wtot[4];
  if (lane == 63) wtot[wv] = inc;
  __syncthreads();
  int wbase = 0;
#pragma unroll
  for (int k = 0; k < 4; ++k) if (k < wv) wbase += wtot[k];
  int run = wbase + (inc - s) + cho[b];
#pragma unroll
  for (int k = 0; k < 8; ++k) {
    int i = base + k;
    if (i < NN) { off[i] = run; cursor[i] = run; }
    run += e[k];
  }
  if (b == 0 && t == 0) off[NN] = NE;
}

// bucket-scatter edges into dst-sorted order as packed (src, w) pairs.
__global__ __launch_bounds__(256) void k_sortedges(const void* ei, const int* __restrict__ flag,
                                                   const float* __restrict__ w,
                                                   int* cursor,
                                                   int2* __restrict__ epair) {
  int e = blockIdx.x * 256 + threadIdx.x;
  if (e >= NE) return;
  int s, d; load_edge(ei, *flag, e, s, d);
  int pos = atomicAdd(&cursor[d], 1);
  epair[pos] = make_int2(s, __float_as_int(w[e]));
}

// sup2 = dinv[:,None] * (x @ W) ; W (128x64 f32 = 32KB) staged in LDS.
__global__ __launch_bounds__(256) void k_gemm(const float* __restrict__ x,
                                              const float* __restrict__ W,
                                              const float* __restrict__ dinv,
                                              float* __restrict__ sup) {
  __shared__ float4 Wl[NF * NH / 4];
  const float4* Wg = (const float4*)W;
  for (int i = threadIdx.x; i < NF * NH / 4; i += 256) Wl[i] = Wg[i];
  __syncthreads();
  int lane16 = threadIdx.x & 15;
  int rowin  = threadIdx.x >> 4;
  const float4* x4 = (const float4*)x;
  float4* s4 = (float4*)sup;
  int rowbase = blockIdx.x * 128;
  for (int r0 = 0; r0 < 128; r0 += 16) {
    int r = rowbase + r0 + rowin;
    if (r >= NN) return;
    float4 acc = make_float4(0.f, 0.f, 0.f, 0.f);
#pragma unroll 8
    for (int kk = 0; kk < NF / 4; ++kk) {
      float4 xv = x4[r * (NF / 4) + kk];
      float4 w0 = Wl[(4 * kk + 0) * 16 + lane16];
      float4 w1 = Wl[(4 * kk + 1) * 16 + lane16];
      float4 w2 = Wl[(4 * kk + 2) * 16 + lane16];
      float4 w3 = Wl[(4 * kk + 3) * 16 + lane16];
      acc.x += xv.x * w0.x + xv.y * w1.x + xv.z * w2.x + xv.w * w3.x;
      acc.y += xv.x * w0.y + xv.y * w1.y + xv.z * w2.y + xv.w * w3.y;
      acc.z += xv.x * w0.z + xv.y * w1.z + xv.z * w2.z + xv.w * w3.z;
      acc.w += xv.x * w0.w + xv.y * w1.w + xv.z * w2.w + xv.w * w3.w;
    }
    float di = dinv[r];
    acc.x *= di; acc.y *= di; acc.z *= di; acc.w *= di;
    s4[r * (NH / 4) + lane16] = acc;
  }
}

// One wave per node: segment-reduce with SCALAR edge loads (uniform j),
// then fused self-loop/bias and Student-t head. z = di*(sum + sup2[i]) + b.
__global__ __launch_bounds__(256) void k_agg_q(const int2* __restrict__ epair,
                                               const int* __restrict__ off,
                                               const float* __restrict__ dinv,
                                               const float* __restrict__ sup,
                                               const float* __restrict__ b,
                                               const float* __restrict__ mu,
                                               float* __restrict__ z,
                                               float* __restrict__ q) {
  __shared__ float mul[NK * NH];
  for (int i = threadIdx.x; i < NK * NH; i += 256) mul[i] = mu[i];
  __syncthreads();
  int wid  = (blockIdx.x * 256 + threadIdx.x) >> 6;  // node
  int lane = threadIdx.x & 63;                       // feature
  if (wid >= NN) return;

  int startU = __builtin_amdgcn_readfirstlane(off[wid]);
  int endU   = __builtin_amdgcn_readfirstlane(off[wid + 1]);
  float di  = dinv[wid];
  float acc = sup[wid * NH + lane];   // self-loop term (sup already dinv-scaled)

  int j = startU;
  for (; j + 4 <= endU; j += 4) {
    int2 e0 = epair[j + 0];
    int2 e1 = epair[j + 1];
    int2 e2 = epair[j + 2];
    int2 e3 = epair[j + 3];
    float v0 = sup[e0.x * NH + lane];
    float v1 = sup[e1.x * NH + lane];
    float v2 = sup[e2.x * NH + lane];
    float v3 = sup[e3.x * NH + lane];
    acc += __int_as_float(e0.y) * v0;
    acc += __int_as_float(e1.y) * v1;
    acc += __int_as_float(e2.y) * v2;
    acc += __int_as_float(e3.y) * v3;
  }
  for (; j < endU; ++j) {
    int2 e0 = epair[j];
    acc += __int_as_float(e0.y) * sup[e0.x * NH + lane];
  }

  float zz = di * acc + b[lane];
  z[wid * NH + lane] = zz;

  // Student-t head
  float d2m = 0.f;
#pragma unroll
  for (int k = 0; k < NK; ++k) {
    float diff = zz - mul[k * NH + lane];
    float s2 = diff * diff;
    for (int o = 32; o; o >>= 1) s2 += __shfl_xor(s2, o, 64);
    if (lane == k) d2m = s2;
  }
  float qv = 0.f;
  if (lane < NK) {
    float tq = 1.0f / (1.0f + d2m * (1.0f / ALPHA) + 1e-8f);
    qv = 0.5f * exp2f((ALPHA + 1.0f) * __log2f(tq));
  }
  float ssum = qv;
  for (int o = 32; o; o >>= 1) ssum += __shfl_xor(ssum, o, 64);
  if (lane < NK) q[wid * NK + lane] = qv / ssum;
}

extern "C" void kernel_launch(void* const* d_in, const int* in_sizes, int n_in,
                              void* d_out, int out_size, void* d_ws, size_t ws_size,
                              hipStream_t stream) {
  const float* x  = (const float*)d_in[0];
  const void*  ei = d_in[1];
  const float* w  = (const float*)d_in[2];
  const float* W  = (const float*)d_in[3];
  const float* b  = (const float*)d_in[4];
  const float* mu = (const float*)d_in[5];

  char* ws = (char*)d_ws;
  int*   flag   = (int*)(ws + O_FLAG);
  float* dinv   = (float*)(ws + O_DEG);
  int*   hist   = (int*)(ws + O_HIST);
  int*   off    = (int*)(ws + O_OFF);
  int*   cursor = (int*)(ws + O_CUR);
  int*   chs    = (int*)(ws + O_CHS);
  int*   cho    = (int*)(ws + O_CHO);
  int2*  epair  = (int2*)(ws + O_EPAIR);
  float* sup    = (float*)(ws + O_SUP);

  float* z = (float*)d_out;
  float* q = (float*)d_out + (size_t)NN * NH;

  hipLaunchKernelGGL(k_detect,    dim3(1),                 dim3(256), 0, stream, ei, flag);
  hipLaunchKernelGGL(k_init,      dim3((NN + 255) / 256),  dim3(256), 0, stream, dinv, hist);
  hipLaunchKernelGGL(k_hist,      dim3((NE + 255) / 256),  dim3(256), 0, stream, ei, flag, w, dinv, hist);
  hipLaunchKernelGGL(k_chsum,     dim3(NCH),               dim3(256), 0, stream, hist, chs, dinv);
  hipLaunchKernelGGL(k_scantop,   dim3(1),                 dim3(64),  0, stream, chs, cho);
  hipLaunchKernelGGL(k_scanapply, dim3(NCH),               dim3(256), 0, stream, hist, cho, off, cursor);
  hipLaunchKernelGGL(k_sortedges, dim3((NE + 255) / 256),  dim3(256), 0, stream, ei, flag, w, cursor, epair);
  hipLaunchKernelGGL(k_gemm,      dim3((NN + 127) / 128),  dim3(256), 0, stream, x, W, dinv, sup);
  hipLaunchKernelGGL(k_agg_q,     dim3((NN * 64) / 256),   dim3(256), 0, stream, epair, off, dinv, sup, b, mu, z, q);
}

// Round 4
// 404.400 us; speedup vs baseline: 1.5889x; 1.1794x over previous
//
#include <hip/hip_runtime.h>

#define NN 100000
#define NE 1600000
#define NF 128
#define NH 64
#define NK 20
#define CH 2048
#define NCH ((NN + CH - 1) / CH)   // 49
#define PAD 8
#define MAXPAIRS (size_t(NE) + size_t(PAD) * NN)   // 2.4M pairs

static constexpr float ALPHA = 0.2f;

typedef unsigned short u16;
typedef unsigned int u32;

// ---- workspace layout (aligned to 256B) ----
constexpr size_t alup(size_t x) { return (x + 255) & ~size_t(255); }
constexpr size_t O_FLAG  = 0;                                   // 4 B
constexpr size_t O_DINV  = 256;                                 // NN f32
constexpr size_t O_HIST  = alup(O_DINV + size_t(NN) * 4);       // NN i32 (real counts)
constexpr size_t O_OFF   = alup(O_HIST + size_t(NN) * 4);       // (NN+1) i32 (padded offsets)
constexpr size_t O_CUR   = alup(O_OFF  + size_t(NN + 1) * 4);   // NN i32
constexpr size_t O_CHS   = alup(O_CUR  + size_t(NN) * 4);       // 64 i32
constexpr size_t O_CHO   = alup(O_CHS  + 64 * 4);               // 64 i32
constexpr size_t O_EPAIR = alup(O_CHO  + 64 * 4);               // MAXPAIRS int2 (src,w) dst-sorted, 0-padded
constexpr size_t O_SUP   = alup(O_EPAIR + MAXPAIRS * 8);        // NN*NH bf16 (12.8 MB), dinv-scaled x@W
// total ~ 33 MB

__device__ __forceinline__ u16 f2bf(float f) {   // RNE float->bf16
  u32 u = __float_as_uint(f);
  u32 r = (u + 0x7fffu + ((u >> 16) & 1u)) >> 16;
  return (u16)r;
}
__device__ __forceinline__ float bf2f(u16 h) {
  return __uint_as_float(((u32)h) << 16);
}

// edge_index dtype probe: int64 data has first 1024 values all in [0,NN).
__global__ __launch_bounds__(256) void k_detect(const void* ei, int* flag) {
  __shared__ int bad;
  if (threadIdx.x == 0) bad = 0;
  __syncthreads();
  const long long* p = (const long long*)ei;
  int ok = 1;
#pragma unroll
  for (int k = 0; k < 4; ++k) {
    long long v = p[threadIdx.x * 4 + k];
    if (v < 0 || v >= NN) ok = 0;
  }
  if (!ok) atomicOr(&bad, 1);
  __syncthreads();
  if (threadIdx.x == 0) *flag = bad ? 0 : 1;
}

__global__ __launch_bounds__(256) void k_init(int* hist) {
  int i = blockIdx.x * 256 + threadIdx.x;
  if (i < NN) hist[i] = 0;
}

// per-edge: hist[dst] += 1   (reads ONLY the dst row of edge_index)
__global__ __launch_bounds__(256) void k_hist(const void* ei, const int* __restrict__ flag,
                                              int* hist) {
  int e = blockIdx.x * 256 + threadIdx.x;
  if (e >= NE) return;
  int d;
  if (*flag) d = (int)((const long long*)ei)[NE + e];
  else       d = ((const int*)ei)[NE + e];
  atomicAdd(&hist[d], 1);
}

// per-chunk sums of PADDED counts (for top-level scan)
__global__ __launch_bounds__(256) void k_chsum(const int* __restrict__ hist, int* chs) {
  int b = blockIdx.x, t = threadIdx.x;
  int base = b * CH + t * 8;
  int s = 0;
#pragma unroll
  for (int k = 0; k < 8; ++k) {
    int i = base + k;
    if (i < NN) s += (hist[i] + (PAD - 1)) & ~(PAD - 1);
  }
  for (int o = 32; o; o >>= 1) s += __shfl_xor(s, o, 64);
  __shared__ int wt[4];
  if ((t & 63) == 0) wt[t >> 6] = s;
  __syncthreads();
  if (t == 0) chs[b] = wt[0] + wt[1] + wt[2] + wt[3];
}

__global__ void k_scantop(const int* __restrict__ chs, int* cho, int* off) {
  int lane = threadIdx.x;  // 64 threads
  int v = lane < NCH ? chs[lane] : 0;
  int inc = v;
  for (int d = 1; d < 64; d <<= 1) { int t = __shfl_up(inc, d, 64); if (lane >= d) inc += t; }
  if (lane < NCH) cho[lane] = inc - v;         // exclusive
  if (lane == NCH - 1) off[NN] = inc;          // total padded count
}

__global__ __launch_bounds__(256) void k_scanapply(const int* __restrict__ hist,
                                                   const int* __restrict__ cho,
                                                   int* off, int* cursor) {
  int b = blockIdx.x, t = threadIdx.x;
  int base = b * CH + t * 8;
  int e[8]; int s = 0;
#pragma unroll
  for (int k = 0; k < 8; ++k) {
    int i = base + k;
    e[k] = (i < NN) ? ((hist[i] + (PAD - 1)) & ~(PAD - 1)) : 0;
    s += e[k];
  }
  int lane = t & 63, wv = t >> 6;
  int inc = s;
  for (int d = 1; d < 64; d <<= 1) { int tt = __shfl_up(inc, d, 64); if (lane >= d) inc += tt; }
  __shared__ int wtot[4];
  if (lane == 63) wtot[wv] = inc;
  __syncthreads();
  int wbase = 0;
#pragma unroll
  for (int k = 0; k < 4; ++k) if (k < wv) wbase += wtot[k];
  int run = wbase + (inc - s) + cho[b];
#pragma unroll
  for (int k = 0; k < 8; ++k) {
    int i = base + k;
    if (i < NN) { off[i] = run; cursor[i] = run; }
    run += e[k];
  }
}

// bucket-scatter edges into dst-sorted order as packed (src, w) pairs.
__global__ __launch_bounds__(256) void k_sortedges(const void* ei, const int* __restrict__ flag,
                                                   const float* __restrict__ w,
                                                   int* cursor,
                                                   int2* __restrict__ epair) {
  int e = blockIdx.x * 256 + threadIdx.x;
  if (e >= NE) return;
  int s, d;
  if (*flag) {
    const long long* p = (const long long*)ei;
    s = (int)p[e]; d = (int)p[NE + e];
  } else {
    const int* p = (const int*)ei;
    s = p[e]; d = p[NE + e];
  }
  int pos = atomicAdd(&cursor[d], 1);
  epair[pos] = make_int2(s, __float_as_int(w[e]));
}

// deg from sorted pairs (pads contribute 0) -> dinv. One thread per node.
__global__ __launch_bounds__(256) void k_degs(const int2* __restrict__ epair,
                                              const int* __restrict__ off,
                                              float* __restrict__ dinv) {
  int i = blockIdx.x * 256 + threadIdx.x;
  if (i >= NN) return;
  int s = off[i], e = off[i + 1];
  float deg = 1.0f;   // self-loop
  for (int j = s; j < e; ++j) deg += __int_as_float(epair[j].y);
  dinv[i] = rsqrtf(deg);
}

// sup = bf16( dinv[:,None] * (x @ W) ) ; W (32KB) staged in LDS.
__global__ __launch_bounds__(256) void k_gemm(const float* __restrict__ x,
                                              const float* __restrict__ W,
                                              const float* __restrict__ dinv,
                                              u16* __restrict__ supb) {
  __shared__ float4 Wl[NF * NH / 4];
  const float4* Wg = (const float4*)W;
  for (int i = threadIdx.x; i < NF * NH / 4; i += 256) Wl[i] = Wg[i];
  __syncthreads();
  int lane16 = threadIdx.x & 15;
  int rowin  = threadIdx.x >> 4;
  const float4* x4 = (const float4*)x;
  int rowbase = blockIdx.x * 128;
  for (int r0 = 0; r0 < 128; r0 += 16) {
    int r = rowbase + r0 + rowin;
    if (r >= NN) return;
    float4 acc = make_float4(0.f, 0.f, 0.f, 0.f);
#pragma unroll 8
    for (int kk = 0; kk < NF / 4; ++kk) {
      float4 xv = x4[r * (NF / 4) + kk];
      float4 w0 = Wl[(4 * kk + 0) * 16 + lane16];
      float4 w1 = Wl[(4 * kk + 1) * 16 + lane16];
      float4 w2 = Wl[(4 * kk + 2) * 16 + lane16];
      float4 w3 = Wl[(4 * kk + 3) * 16 + lane16];
      acc.x += xv.x * w0.x + xv.y * w1.x + xv.z * w2.x + xv.w * w3.x;
      acc.y += xv.x * w0.y + xv.y * w1.y + xv.z * w2.y + xv.w * w3.y;
      acc.z += xv.x * w0.z + xv.y * w1.z + xv.z * w2.z + xv.w * w3.z;
      acc.w += xv.x * w0.w + xv.y * w1.w + xv.z * w2.w + xv.w * w3.w;
    }
    float di = dinv[r];
    ushort4 o;
    o.x = f2bf(acc.x * di); o.y = f2bf(acc.y * di);
    o.z = f2bf(acc.z * di); o.w = f2bf(acc.w * di);
    *(ushort4*)&supb[(size_t)r * NH + lane16 * 4] = o;
  }
}

// One wave per node: padded segment-reduce with scalar edge loads (uniform j,
// 8 gathers in flight), then fused self-loop/bias and Student-t head.
__global__ __launch_bounds__(256) void k_agg_q(const int2* __restrict__ epair,
                                               const int* __restrict__ off,
                                               const float* __restrict__ dinv,
                                               const u16* __restrict__ supb,
                                               const float* __restrict__ b,
                                               const float* __restrict__ mu,
                                               float* __restrict__ z,
                                               float* __restrict__ q) {
  __shared__ float mul[NK * NH];
  for (int i = threadIdx.x; i < NK * NH; i += 256) mul[i] = mu[i];
  __syncthreads();
  int wid  = (blockIdx.x * 256 + threadIdx.x) >> 6;  // node
  int lane = threadIdx.x & 63;                       // feature
  if (wid >= NN) return;

  int startU = __builtin_amdgcn_readfirstlane(off[wid]);
  int endU   = __builtin_amdgcn_readfirstlane(off[wid + 1]);
  float di  = dinv[wid];
  float acc0 = bf2f(supb[(size_t)wid * NH + lane]);  // self-loop term
  float acc1 = 0.f;

  for (int j = startU; j < endU; j += 8) {
    int2 e0 = epair[j + 0], e1 = epair[j + 1], e2 = epair[j + 2], e3 = epair[j + 3];
    int2 e4 = epair[j + 4], e5 = epair[j + 5], e6 = epair[j + 6], e7 = epair[j + 7];
    const u16* p0 = supb + ((size_t)e0.x << 6);
    const u16* p1 = supb + ((size_t)e1.x << 6);
    const u16* p2 = supb + ((size_t)e2.x << 6);
    const u16* p3 = supb + ((size_t)e3.x << 6);
    const u16* p4 = supb + ((size_t)e4.x << 6);
    const u16* p5 = supb + ((size_t)e5.x << 6);
    const u16* p6 = supb + ((size_t)e6.x << 6);
    const u16* p7 = supb + ((size_t)e7.x << 6);
    float v0 = bf2f(p0[lane]);
    float v1 = bf2f(p1[lane]);
    float v2 = bf2f(p2[lane]);
    float v3 = bf2f(p3[lane]);
    float v4 = bf2f(p4[lane]);
    float v5 = bf2f(p5[lane]);
    float v6 = bf2f(p6[lane]);
    float v7 = bf2f(p7[lane]);
    acc0 += __int_as_float(e0.y) * v0;
    acc1 += __int_as_float(e1.y) * v1;
    acc0 += __int_as_float(e2.y) * v2;
    acc1 += __int_as_float(e3.y) * v3;
    acc0 += __int_as_float(e4.y) * v4;
    acc1 += __int_as_float(e5.y) * v5;
    acc0 += __int_as_float(e6.y) * v6;
    acc1 += __int_as_float(e7.y) * v7;
  }

  float zz = di * (acc0 + acc1) + b[lane];
  z[(size_t)wid * NH + lane] = zz;

  // Student-t head
  float d2m = 0.f;
#pragma unroll
  for (int k = 0; k < NK; ++k) {
    float diff = zz - mul[k * NH + lane];
    float s2 = diff * diff;
    for (int o = 32; o; o >>= 1) s2 += __shfl_xor(s2, o, 64);
    if (lane == k) d2m = s2;
  }
  float qv = 0.f;
  if (lane < NK) {
    float tq = 1.0f / (1.0f + d2m * (1.0f / ALPHA) + 1e-8f);
    qv = 0.5f * exp2f((ALPHA + 1.0f) * __log2f(tq));
  }
  float ssum = qv;
  for (int o = 32; o; o >>= 1) ssum += __shfl_xor(ssum, o, 64);
  if (lane < NK) q[(size_t)wid * NK + lane] = qv / ssum;
}

extern "C" void kernel_launch(void* const* d_in, const int* in_sizes, int n_in,
                              void* d_out, int out_size, void* d_ws, size_t ws_size,
                              hipStream_t stream) {
  const float* x  = (const float*)d_in[0];
  const void*  ei = d_in[1];
  const float* w  = (const float*)d_in[2];
  const float* W  = (const float*)d_in[3];
  const float* b  = (const float*)d_in[4];
  const float* mu = (const float*)d_in[5];

  char* ws = (char*)d_ws;
  int*   flag   = (int*)(ws + O_FLAG);
  float* dinv   = (float*)(ws + O_DINV);
  int*   hist   = (int*)(ws + O_HIST);
  int*   off    = (int*)(ws + O_OFF);
  int*   cursor = (int*)(ws + O_CUR);
  int*   chs    = (int*)(ws + O_CHS);
  int*   cho    = (int*)(ws + O_CHO);
  int2*  epair  = (int2*)(ws + O_EPAIR);
  u16*   supb   = (u16*)(ws + O_SUP);

  float* z = (float*)d_out;
  float* q = (float*)d_out + (size_t)NN * NH;

  hipMemsetAsync(epair, 0, MAXPAIRS * 8, stream);   // zero pads (w=0, src=0)
  hipLaunchKernelGGL(k_detect,    dim3(1),                 dim3(256), 0, stream, ei, flag);
  hipLaunchKernelGGL(k_init,      dim3((NN + 255) / 256),  dim3(256), 0, stream, hist);
  hipLaunchKernelGGL(k_hist,      dim3((NE + 255) / 256),  dim3(256), 0, stream, ei, flag, hist);
  hipLaunchKernelGGL(k_chsum,     dim3(NCH),               dim3(256), 0, stream, hist, chs);
  hipLaunchKernelGGL(k_scantop,   dim3(1),                 dim3(64),  0, stream, chs, cho, off);
  hipLaunchKernelGGL(k_scanapply, dim3(NCH),               dim3(256), 0, stream, hist, cho, off, cursor);
  hipLaunchKernelGGL(k_sortedges, dim3((NE + 255) / 256),  dim3(256), 0, stream, ei, flag, w, cursor, epair);
  hipLaunchKernelGGL(k_degs,      dim3((NN + 255) / 256),  dim3(256), 0, stream, epair, off, dinv);
  hipLaunchKernelGGL(k_gemm,      dim3((NN + 127) / 128),  dim3(256), 0, stream, x, W, dinv, supb);
  hipLaunchKernelGGL(k_agg_q,     dim3((NN * 64) / 256),   dim3(256), 0, stream, epair, off, dinv, supb, b, mu, z, q);
}

// Round 5
// 344.571 us; speedup vs baseline: 1.8647x; 1.1736x over previous
//
#include <hip/hip_runtime.h>

#define NN 100000
#define NE 1600000
#define NF 128
#define NH 64
#define NK 20
#define CH 2048
#define NCH ((NN + CH - 1) / CH)   // 49
#define PAD 8
#define MAXPAIRS (size_t(NE) + size_t(PAD) * NN)   // 2.4M pairs

static constexpr float ALPHA = 0.2f;

typedef unsigned short u16;
typedef unsigned int u32;

// ---- workspace layout (aligned to 256B) ----
constexpr size_t alup(size_t x) { return (x + 255) & ~size_t(255); }
constexpr size_t O_FLAG  = 0;                                   // 4 B
constexpr size_t O_DINV  = 256;                                 // NN f32
constexpr size_t O_HIST  = alup(O_DINV + size_t(NN) * 4);       // NN i32 (real counts)
constexpr size_t O_OFF   = alup(O_HIST + size_t(NN) * 4);       // (NN+1) i32 (padded offsets)
constexpr size_t O_CUR   = alup(O_OFF  + size_t(NN + 1) * 4);   // NN i32
constexpr size_t O_CHS   = alup(O_CUR  + size_t(NN) * 4);       // 64 i32
constexpr size_t O_CHO   = alup(O_CHS  + 64 * 4);               // 64 i32
constexpr size_t O_EPAIR = alup(O_CHO  + 64 * 4);               // MAXPAIRS int2 (src,w) dst-sorted, 0-padded
constexpr size_t O_SUP   = alup(O_EPAIR + MAXPAIRS * 8);        // NN*NH bf16 (12.8 MB), dinv-scaled x@W
// total ~ 33 MB

__device__ __forceinline__ u16 f2bf(float f) {   // RNE float->bf16
  u32 u = __float_as_uint(f);
  u32 r = (u + 0x7fffu + ((u >> 16) & 1u)) >> 16;
  return (u16)r;
}
__device__ __forceinline__ float bf2f(u16 h) {
  return __uint_as_float(((u32)h) << 16);
}

// edge_index dtype probe: int64 data has first 1024 values all in [0,NN).
__global__ __launch_bounds__(256) void k_detect(const void* ei, int* flag) {
  __shared__ int bad;
  if (threadIdx.x == 0) bad = 0;
  __syncthreads();
  const long long* p = (const long long*)ei;
  int ok = 1;
#pragma unroll
  for (int k = 0; k < 4; ++k) {
    long long v = p[threadIdx.x * 4 + k];
    if (v < 0 || v >= NN) ok = 0;
  }
  if (!ok) atomicOr(&bad, 1);
  __syncthreads();
  if (threadIdx.x == 0) *flag = bad ? 0 : 1;
}

// per-edge: hist[dst] += 1. 4 edges/thread, vectorized dst reads.
__global__ __launch_bounds__(256) void k_hist(const void* ei, const int* __restrict__ flag,
                                              int* hist) {
  int e = (blockIdx.x * 256 + threadIdx.x) * 4;
  if (e >= NE) return;
  int d0, d1, d2, d3;
  if (*flag) {
    const long long* p = (const long long*)ei + NE;
    longlong2 a = *(const longlong2*)(p + e);
    longlong2 b = *(const longlong2*)(p + e + 2);
    d0 = (int)a.x; d1 = (int)a.y; d2 = (int)b.x; d3 = (int)b.y;
  } else {
    const int* p = (const int*)ei + NE;
    int4 v = *(const int4*)(p + e);
    d0 = v.x; d1 = v.y; d2 = v.z; d3 = v.w;
  }
  atomicAdd(&hist[d0], 1); atomicAdd(&hist[d1], 1);
  atomicAdd(&hist[d2], 1); atomicAdd(&hist[d3], 1);
}

// per-chunk sums of PADDED counts (for top-level scan)
__global__ __launch_bounds__(256) void k_chsum(const int* __restrict__ hist, int* chs) {
  int b = blockIdx.x, t = threadIdx.x;
  int base = b * CH + t * 8;
  int s = 0;
#pragma unroll
  for (int k = 0; k < 8; ++k) {
    int i = base + k;
    if (i < NN) s += (hist[i] + (PAD - 1)) & ~(PAD - 1);
  }
  for (int o = 32; o; o >>= 1) s += __shfl_xor(s, o, 64);
  __shared__ int wt[4];
  if ((t & 63) == 0) wt[t >> 6] = s;
  __syncthreads();
  if (t == 0) chs[b] = wt[0] + wt[1] + wt[2] + wt[3];
}

__global__ void k_scantop(const int* __restrict__ chs, int* cho, int* off) {
  int lane = threadIdx.x;  // 64 threads
  int v = lane < NCH ? chs[lane] : 0;
  int inc = v;
  for (int d = 1; d < 64; d <<= 1) { int t = __shfl_up(inc, d, 64); if (lane >= d) inc += t; }
  if (lane < NCH) cho[lane] = inc - v;         // exclusive
  if (lane == NCH - 1) off[NN] = inc;          // total padded count
}

__global__ __launch_bounds__(256) void k_scanapply(const int* __restrict__ hist,
                                                   const int* __restrict__ cho,
                                                   int* off, int* cursor) {
  int b = blockIdx.x, t = threadIdx.x;
  int base = b * CH + t * 8;
  int e[8]; int s = 0;
#pragma unroll
  for (int k = 0; k < 8; ++k) {
    int i = base + k;
    e[k] = (i < NN) ? ((hist[i] + (PAD - 1)) & ~(PAD - 1)) : 0;
    s += e[k];
  }
  int lane = t & 63, wv = t >> 6;
  int inc = s;
  for (int d = 1; d < 64; d <<= 1) { int tt = __shfl_up(inc, d, 64); if (lane >= d) inc += tt; }
  __shared__ int wtot[4];
  if (lane == 63) wtot[wv] = inc;
  __syncthreads();
  int wbase = 0;
#pragma unroll
  for (int k = 0; k < 4; ++k) if (k < wv) wbase += wtot[k];
  int run = wbase + (inc - s) + cho[b];
#pragma unroll
  for (int k = 0; k < 8; ++k) {
    int i = base + k;
    if (i < NN) { off[i] = run; cursor[i] = run; }
    run += e[k];
  }
}

// bucket-scatter edges into dst-sorted order as packed (src, w) pairs. 2 edges/thread.
__global__ __launch_bounds__(256) void k_sortedges(const void* ei, const int* __restrict__ flag,
                                                   const float* __restrict__ w,
                                                   int* cursor,
                                                   int2* __restrict__ epair) {
  int e = (blockIdx.x * 256 + threadIdx.x) * 2;
  if (e >= NE) return;
  int s0, s1, d0, d1;
  if (*flag) {
    const long long* p = (const long long*)ei;
    longlong2 sv = *(const longlong2*)(p + e);
    longlong2 dv = *(const longlong2*)(p + NE + e);
    s0 = (int)sv.x; s1 = (int)sv.y; d0 = (int)dv.x; d1 = (int)dv.y;
  } else {
    const int* p = (const int*)ei;
    int2 sv = *(const int2*)(p + e);
    int2 dv = *(const int2*)(p + NE + e);
    s0 = sv.x; s1 = sv.y; d0 = dv.x; d1 = dv.y;
  }
  float2 wv = *(const float2*)(w + e);
  int p0 = atomicAdd(&cursor[d0], 1);
  epair[p0] = make_int2(s0, __float_as_int(wv.x));
  int p1 = atomicAdd(&cursor[d1], 1);
  epair[p1] = make_int2(s1, __float_as_int(wv.y));
}

// deg from sorted pairs (pads contribute 0) -> dinv. One thread per node.
__global__ __launch_bounds__(256) void k_degs(const int2* __restrict__ epair,
                                              const int* __restrict__ off,
                                              float* __restrict__ dinv) {
  int i = blockIdx.x * 256 + threadIdx.x;
  if (i >= NN) return;
  int s = off[i], e = off[i + 1];
  float deg = 1.0f;   // self-loop
  for (int j = s; j < e; ++j) deg += __int_as_float(epair[j].y);
  dinv[i] = rsqrtf(deg);
}

// sup = bf16( dinv[:,None] * (x @ W) ) ; W (32KB) staged in LDS.
__global__ __launch_bounds__(256) void k_gemm(const float* __restrict__ x,
                                              const float* __restrict__ W,
                                              const float* __restrict__ dinv,
                                              u16* __restrict__ supb) {
  __shared__ float4 Wl[NF * NH / 4];
  const float4* Wg = (const float4*)W;
  for (int i = threadIdx.x; i < NF * NH / 4; i += 256) Wl[i] = Wg[i];
  __syncthreads();
  int lane16 = threadIdx.x & 15;
  int rowin  = threadIdx.x >> 4;
  const float4* x4 = (const float4*)x;
  int rowbase = blockIdx.x * 128;
  for (int r0 = 0; r0 < 128; r0 += 16) {
    int r = rowbase + r0 + rowin;
    if (r >= NN) return;
    float4 acc = make_float4(0.f, 0.f, 0.f, 0.f);
#pragma unroll 8
    for (int kk = 0; kk < NF / 4; ++kk) {
      float4 xv = x4[r * (NF / 4) + kk];
      float4 w0 = Wl[(4 * kk + 0) * 16 + lane16];
      float4 w1 = Wl[(4 * kk + 1) * 16 + lane16];
      float4 w2 = Wl[(4 * kk + 2) * 16 + lane16];
      float4 w3 = Wl[(4 * kk + 3) * 16 + lane16];
      acc.x += xv.x * w0.x + xv.y * w1.x + xv.z * w2.x + xv.w * w3.x;
      acc.y += xv.x * w0.y + xv.y * w1.y + xv.z * w2.y + xv.w * w3.y;
      acc.z += xv.x * w0.z + xv.y * w1.z + xv.z * w2.z + xv.w * w3.z;
      acc.w += xv.x * w0.w + xv.y * w1.w + xv.z * w2.w + xv.w * w3.w;
    }
    float di = dinv[r];
    ushort4 o;
    o.x = f2bf(acc.x * di); o.y = f2bf(acc.y * di);
    o.z = f2bf(acc.z * di); o.w = f2bf(acc.w * di);
    *(ushort4*)&supb[(size_t)r * NH + lane16 * 4] = o;
  }
}

// One wave per node: padded segment-reduce with scalar edge loads (uniform j,
// 8 gathers in flight), then LDS-transpose Student-t head (no swizzle storm:
// lane k<20 computes d2_k directly from the wave's z row in LDS).
__global__ __launch_bounds__(256) void k_agg_q(const int2* __restrict__ epair,
                                               const int* __restrict__ off,
                                               const float* __restrict__ dinv,
                                               const u16* __restrict__ supb,
                                               const float* __restrict__ b,
                                               const float* __restrict__ mu,
                                               float* __restrict__ z,
                                               float* __restrict__ q) {
  __shared__ float muL[NK * 68];    // padded rows: stride 68 words breaks bank aliasing
  __shared__ float zsh[4][64];      // one z row per wave
  for (int i = threadIdx.x; i < NK * NH; i += 256) muL[(i >> 6) * 68 + (i & 63)] = mu[i];
  __syncthreads();
  int wid  = (blockIdx.x * 256 + threadIdx.x) >> 6;  // node
  int lane = threadIdx.x & 63;                       // feature
  int wv   = threadIdx.x >> 6;                       // wave in block

  int startU = __builtin_amdgcn_readfirstlane(off[wid]);
  int endU   = __builtin_amdgcn_readfirstlane(off[wid + 1]);
  float di  = dinv[wid];
  float acc0 = bf2f(supb[(size_t)wid * NH + lane]);  // self-loop term
  float acc1 = 0.f;

  for (int j = startU; j < endU; j += 8) {
    int2 e0 = epair[j + 0], e1 = epair[j + 1], e2 = epair[j + 2], e3 = epair[j + 3];
    int2 e4 = epair[j + 4], e5 = epair[j + 5], e6 = epair[j + 6], e7 = epair[j + 7];
    const u16* p0 = supb + ((size_t)e0.x << 6);
    const u16* p1 = supb + ((size_t)e1.x << 6);
    const u16* p2 = supb + ((size_t)e2.x << 6);
    const u16* p3 = supb + ((size_t)e3.x << 6);
    const u16* p4 = supb + ((size_t)e4.x << 6);
    const u16* p5 = supb + ((size_t)e5.x << 6);
    const u16* p6 = supb + ((size_t)e6.x << 6);
    const u16* p7 = supb + ((size_t)e7.x << 6);
    float v0 = bf2f(p0[lane]);
    float v1 = bf2f(p1[lane]);
    float v2 = bf2f(p2[lane]);
    float v3 = bf2f(p3[lane]);
    float v4 = bf2f(p4[lane]);
    float v5 = bf2f(p5[lane]);
    float v6 = bf2f(p6[lane]);
    float v7 = bf2f(p7[lane]);
    acc0 += __int_as_float(e0.y) * v0;
    acc1 += __int_as_float(e1.y) * v1;
    acc0 += __int_as_float(e2.y) * v2;
    acc1 += __int_as_float(e3.y) * v3;
    acc0 += __int_as_float(e4.y) * v4;
    acc1 += __int_as_float(e5.y) * v5;
    acc0 += __int_as_float(e6.y) * v6;
    acc1 += __int_as_float(e7.y) * v7;
  }

  float zz = di * (acc0 + acc1) + b[lane];
  z[(size_t)wid * NH + lane] = zz;
  zsh[wv][lane] = zz;   // same-wave write->read; compiler inserts lgkmcnt wait

  float qv = 0.f;
  if (lane < NK) {
    const float4* zr = (const float4*)zsh[wv];          // broadcast reads
    const float4* mr = (const float4*)&muL[lane * 68];  // per-lane mu row
    float s0 = 0.f, s1 = 0.f, s2 = 0.f, s3 = 0.f;
#pragma unroll
    for (int j = 0; j < 16; ++j) {
      float4 zv = zr[j];
      float4 mv = mr[j];
      float a0 = zv.x - mv.x, a1 = zv.y - mv.y, a2 = zv.z - mv.z, a3 = zv.w - mv.w;
      s0 += a0 * a0; s1 += a1 * a1; s2 += a2 * a2; s3 += a3 * a3;
    }
    float d2 = (s0 + s1) + (s2 + s3);
    float tq = 1.0f / (1.0f + d2 * (1.0f / ALPHA) + 1e-8f);
    qv = exp2f((ALPHA + 1.0f) * __log2f(tq));   // the /2 factor cancels in normalization
  }
  float ssum = qv;
  for (int o = 32; o; o >>= 1) ssum += __shfl_xor(ssum, o, 64);
  if (lane < NK) q[(size_t)wid * NK + lane] = qv / ssum;
}

extern "C" void kernel_launch(void* const* d_in, const int* in_sizes, int n_in,
                              void* d_out, int out_size, void* d_ws, size_t ws_size,
                              hipStream_t stream) {
  const float* x  = (const float*)d_in[0];
  const void*  ei = d_in[1];
  const float* w  = (const float*)d_in[2];
  const float* W  = (const float*)d_in[3];
  const float* b  = (const float*)d_in[4];
  const float* mu = (const float*)d_in[5];

  char* ws = (char*)d_ws;
  int*   flag   = (int*)(ws + O_FLAG);
  float* dinv   = (float*)(ws + O_DINV);
  int*   hist   = (int*)(ws + O_HIST);
  int*   off    = (int*)(ws + O_OFF);
  int*   cursor = (int*)(ws + O_CUR);
  int*   chs    = (int*)(ws + O_CHS);
  int*   cho    = (int*)(ws + O_CHO);
  int2*  epair  = (int2*)(ws + O_EPAIR);
  u16*   supb   = (u16*)(ws + O_SUP);

  float* z = (float*)d_out;
  float* q = (float*)d_out + (size_t)NN * NH;

  hipMemsetAsync(epair, 0, MAXPAIRS * 8, stream);   // zero pads (w=0, src=0)
  hipMemsetAsync(hist, 0, size_t(NN) * 4, stream);
  hipLaunchKernelGGL(k_detect,    dim3(1),                     dim3(256), 0, stream, ei, flag);
  hipLaunchKernelGGL(k_hist,      dim3((NE / 4 + 255) / 256),  dim3(256), 0, stream, ei, flag, hist);
  hipLaunchKernelGGL(k_chsum,     dim3(NCH),                   dim3(256), 0, stream, hist, chs);
  hipLaunchKernelGGL(k_scantop,   dim3(1),                     dim3(64),  0, stream, chs, cho, off);
  hipLaunchKernelGGL(k_scanapply, dim3(NCH),                   dim3(256), 0, stream, hist, cho, off, cursor);
  hipLaunchKernelGGL(k_sortedges, dim3((NE / 2 + 255) / 256),  dim3(256), 0, stream, ei, flag, w, cursor, epair);
  hipLaunchKernelGGL(k_degs,      dim3((NN + 255) / 256),      dim3(256), 0, stream, epair, off, dinv);
  hipLaunchKernelGGL(k_gemm,      dim3((NN + 127) / 128),      dim3(256), 0, stream, x, W, dinv, supb);
  hipLaunchKernelGGL(k_agg_q,     dim3((NN * 64) / 256),       dim3(256), 0, stream, epair, off, dinv, supb, b, mu, z, q);
}

// Round 6
// 204.532 us; speedup vs baseline: 3.1415x; 1.6847x over previous
//
#include <hip/hip_runtime.h>

#define NN 100000
#define NE 1600000
#define NF 128
#define NH 64
#define NK 20
#define CH 2048
#define NCH ((NN + CH - 1) / CH)   // 49  (offset-scan chunks)
#define SBK 512                     // sort-bucket: nodes per bucket
#define NSB ((NN + SBK - 1) / SBK)  // 196 buckets
#define CT 4096                     // edges per coarse-scatter block
#define PAD 8
#define MAXPAIRS (size_t(NE) + size_t(PAD) * NN)   // 2.4M pairs

static constexpr float ALPHA = 0.2f;

typedef unsigned short u16;
typedef unsigned int u32;

// ---- workspace layout (aligned to 256B) ----
constexpr size_t alup(size_t x) { return (x + 255) & ~size_t(255); }
constexpr size_t O_FLAG   = 0;                                    // 4 B
constexpr size_t O_DINV   = 256;                                  // NN f32
constexpr size_t O_HIST   = alup(O_DINV + size_t(NN) * 4);        // NN i32 (real counts)
constexpr size_t O_OFF    = alup(O_HIST + size_t(NN) * 4);        // (NN+1) i32 (padded offsets)
constexpr size_t O_CHS    = alup(O_OFF  + size_t(NN + 1) * 4);    // 64 i32
constexpr size_t O_CHO    = alup(O_CHS  + 64 * 4);                // 64 i32
constexpr size_t O_GBH    = alup(O_CHO  + 64 * 4);                // NSB i32 (bucket counts, zeroed)
constexpr size_t O_BBASE  = alup(O_GBH  + size_t(NSB) * 4);       // NSB+1 i32
constexpr size_t O_BCUR   = alup(O_BBASE + size_t(NSB + 1) * 4);  // NSB i32
constexpr size_t O_COARSE = alup(O_BCUR + size_t(NSB) * 4);       // NE uint2 (12.8 MB) bucket-grouped
constexpr size_t O_EPAIR  = alup(O_COARSE + size_t(NE) * 8);      // MAXPAIRS int2 (19.2 MB) node-sorted, 0-padded
constexpr size_t O_SUP    = alup(O_EPAIR + MAXPAIRS * 8);         // NN*NH bf16 (12.8 MB), dinv-scaled x@W
// total ~ 46 MB

__device__ __forceinline__ u16 f2bf(float f) {   // RNE float->bf16
  u32 u = __float_as_uint(f);
  u32 r = (u + 0x7fffu + ((u >> 16) & 1u)) >> 16;
  return (u16)r;
}
__device__ __forceinline__ float bf2f(u16 h) {
  return __uint_as_float(((u32)h) << 16);
}

// edge_index dtype probe: int64 data has first 1024 values all in [0,NN).
__global__ __launch_bounds__(256) void k_detect(const void* ei, int* flag) {
  __shared__ int bad;
  if (threadIdx.x == 0) bad = 0;
  __syncthreads();
  const long long* p = (const long long*)ei;
  int ok = 1;
#pragma unroll
  for (int k = 0; k < 4; ++k) {
    long long v = p[threadIdx.x * 4 + k];
    if (v < 0 || v >= NN) ok = 0;
  }
  if (!ok) atomicOr(&bad, 1);
  __syncthreads();
  if (threadIdx.x == 0) *flag = bad ? 0 : 1;
}

// bucket histogram (196 bins) via LDS, one global atomic per bin per block.
__global__ __launch_bounds__(256) void k_bhist(const void* ei, const int* __restrict__ flag,
                                               int* gbh) {
  __shared__ int lh[NSB];
  int t = threadIdx.x;
  for (int i = t; i < NSB; i += 256) lh[i] = 0;
  __syncthreads();
  int base = blockIdx.x * CT;
  int is64 = *flag;
#pragma unroll
  for (int k = 0; k < 16; ++k) {
    int e = base + k * 256 + t;
    if (e < NE) {
      int d;
      if (is64) d = (int)((const long long*)ei)[NE + e];
      else      d = ((const int*)ei)[NE + e];
      atomicAdd(&lh[d >> 9], 1);
    }
  }
  __syncthreads();
  if (t < NSB) { int c = lh[t]; if (c) atomicAdd(&gbh[t], c); }
}

// exclusive scan of 196 bucket counts (single block).
__global__ __launch_bounds__(256) void k_bscan(const int* __restrict__ gbh,
                                               int* bbase, int* bcur) {
  __shared__ int sh[256];
  int t = threadIdx.x;
  int v = (t < NSB) ? gbh[t] : 0;
  sh[t] = v;
  __syncthreads();
  int acc = v;
  for (int d = 1; d < 256; d <<= 1) {
    int add = (t >= d) ? sh[t - d] : 0;
    __syncthreads();
    acc += add; sh[t] = acc;
    __syncthreads();
  }
  int excl = acc - v;
  if (t < NSB) { bbase[t] = excl; bcur[t] = excl; }
  if (t == NSB - 1) bbase[NSB] = excl + v;   // = NE
}

// coarse scatter: bin edges by dst-bucket; LDS ranking makes each block's
// same-bucket writes contiguous -> bucket frontier (196 lines) stays in L2.
__global__ __launch_bounds__(256) void k_coarse(const void* ei, const int* __restrict__ flag,
                                                const float* __restrict__ w,
                                                int* bcur, uint2* __restrict__ coarse) {
  __shared__ int lh[NSB];
  __shared__ int lbase[NSB];
  int t = threadIdx.x;
  for (int i = t; i < NSB; i += 256) lh[i] = 0;
  __syncthreads();
  int base = blockIdx.x * CT;
  int is64 = *flag;
  u32 key[16]; int wb[16], bk[16], lr[16];
#pragma unroll
  for (int k = 0; k < 16; ++k) {
    int e = base + k * 256 + t;
    if (e < NE) {
      int s, d;
      if (is64) { const long long* p = (const long long*)ei; s = (int)p[e]; d = (int)p[NE + e]; }
      else      { const int*       p = (const int*)ei;       s = p[e];      d = p[NE + e]; }
      int b = d >> 9, dlo = d & 511;
      key[k] = (u32)s | ((u32)dlo << 17);     // src:17 bits | dstlo:9 bits
      wb[k]  = __float_as_int(w[e]);
      bk[k]  = b;
      lr[k]  = atomicAdd(&lh[b], 1);
    }
  }
  __syncthreads();
  if (t < NSB) { int c = lh[t]; if (c) lbase[t] = atomicAdd(&bcur[t], c); }
  __syncthreads();
#pragma unroll
  for (int k = 0; k < 16; ++k) {
    int e = base + k * 256 + t;
    if (e < NE) coarse[lbase[bk[k]] + lr[k]] = make_uint2(key[k], (u32)wb[k]);
  }
}

// per-node counts + weighted degree from the bucket-grouped coarse array.
// No global atomics; coalesced hist/dinv writes.
__global__ __launch_bounds__(256) void k_nhist(const uint2* __restrict__ coarse,
                                               const int* __restrict__ bbase,
                                               int* __restrict__ hist,
                                               float* __restrict__ dinv) {
  __shared__ int cnt[SBK];
  __shared__ float wsum[SBK];
  int t = threadIdx.x, b = blockIdx.x;
  for (int i = t; i < SBK; i += 256) { cnt[i] = 0; wsum[i] = 0.f; }
  __syncthreads();
  int s = bbase[b], e = bbase[b + 1];
  for (int j = s + t; j < e; j += 256) {
    uint2 u = coarse[j];
    int dlo = u.x >> 17;
    atomicAdd(&cnt[dlo], 1);
    atomicAdd(&wsum[dlo], __uint_as_float(u.y));
  }
  __syncthreads();
  for (int i = t; i < SBK; i += 256) {
    int node = b * SBK + i;
    if (node < NN) { hist[node] = cnt[i]; dinv[node] = rsqrtf(1.0f + wsum[i]); }
  }
}

// per-chunk sums of PADDED counts (for top-level offset scan)
__global__ __launch_bounds__(256) void k_chsum(const int* __restrict__ hist, int* chs) {
  int b = blockIdx.x, t = threadIdx.x;
  int base = b * CH + t * 8;
  int s = 0;
#pragma unroll
  for (int k = 0; k < 8; ++k) {
    int i = base + k;
    if (i < NN) s += (hist[i] + (PAD - 1)) & ~(PAD - 1);
  }
  for (int o = 32; o; o >>= 1) s += __shfl_xor(s, o, 64);
  __shared__ int wt[4];
  if ((t & 63) == 0) wt[t >> 6] = s;
  __syncthreads();
  if (t == 0) chs[b] = wt[0] + wt[1] + wt[2] + wt[3];
}

__global__ void k_scantop(const int* __restrict__ chs, int* cho, int* off) {
  int lane = threadIdx.x;  // 64 threads
  int v = lane < NCH ? chs[lane] : 0;
  int inc = v;
  for (int d = 1; d < 64; d <<= 1) { int t = __shfl_up(inc, d, 64); if (lane >= d) inc += t; }
  if (lane < NCH) cho[lane] = inc - v;         // exclusive
  if (lane == NCH - 1) off[NN] = inc;          // total padded count
}

__global__ __launch_bounds__(256) void k_scanapply(const int* __restrict__ hist,
                                                   const int* __restrict__ cho,
                                                   int* off) {
  int b = blockIdx.x, t = threadIdx.x;
  int base = b * CH + t * 8;
  int e[8]; int s = 0;
#pragma unroll
  for (int k = 0; k < 8; ++k) {
    int i = base + k;
    e[k] = (i < NN) ? ((hist[i] + (PAD - 1)) & ~(PAD - 1)) : 0;
    s += e[k];
  }
  int lane = t & 63, wv = t >> 6;
  int inc = s;
  for (int d = 1; d < 64; d <<= 1) { int tt = __shfl_up(inc, d, 64); if (lane >= d) inc += tt; }
  __shared__ int wtot[4];
  if (lane == 63) wtot[wv] = inc;
  __syncthreads();
  int wbase = 0;
#pragma unroll
  for (int k = 0; k < 4; ++k) if (k < wv) wbase += wtot[k];
  int run = wbase + (inc - s) + cho[b];
#pragma unroll
  for (int k = 0; k < 8; ++k) {
    int i = base + k;
    if (i < NN) off[i] = run;
    run += e[k];
  }
}

// fine scatter: one block per bucket; LDS per-node cursors; writes confined
// to the bucket's ~75 KB final window -> lines fill in L2, no amplification.
__global__ __launch_bounds__(256) void k_fine(const uint2* __restrict__ coarse,
                                              const int* __restrict__ bbase,
                                              const int* __restrict__ off,
                                              int2* __restrict__ epair) {
  __shared__ int cur[SBK];
  int t = threadIdx.x, b = blockIdx.x;
  for (int i = t; i < SBK; i += 256) {
    int node = b * SBK + i;
    cur[i] = (node < NN) ? off[node] : 0;
  }
  __syncthreads();
  int s = bbase[b], e = bbase[b + 1];
  for (int j = s + t; j < e; j += 256) {
    uint2 u = coarse[j];
    int dlo = u.x >> 17;
    int src = u.x & 0x1FFFF;
    int pos = atomicAdd(&cur[dlo], 1);
    epair[pos] = make_int2(src, (int)u.y);
  }
}

// sup = bf16( dinv[:,None] * (x @ W) ) ; W (32KB) staged in LDS.
__global__ __launch_bounds__(256) void k_gemm(const float* __restrict__ x,
                                              const float* __restrict__ W,
                                              const float* __restrict__ dinv,
                                              u16* __restrict__ supb) {
  __shared__ float4 Wl[NF * NH / 4];
  const float4* Wg = (const float4*)W;
  for (int i = threadIdx.x; i < NF * NH / 4; i += 256) Wl[i] = Wg[i];
  __syncthreads();
  int lane16 = threadIdx.x & 15;
  int rowin  = threadIdx.x >> 4;
  const float4* x4 = (const float4*)x;
  int rowbase = blockIdx.x * 128;
  for (int r0 = 0; r0 < 128; r0 += 16) {
    int r = rowbase + r0 + rowin;
    if (r >= NN) return;
    float4 acc = make_float4(0.f, 0.f, 0.f, 0.f);
#pragma unroll 8
    for (int kk = 0; kk < NF / 4; ++kk) {
      float4 xv = x4[r * (NF / 4) + kk];
      float4 w0 = Wl[(4 * kk + 0) * 16 + lane16];
      float4 w1 = Wl[(4 * kk + 1) * 16 + lane16];
      float4 w2 = Wl[(4 * kk + 2) * 16 + lane16];
      float4 w3 = Wl[(4 * kk + 3) * 16 + lane16];
      acc.x += xv.x * w0.x + xv.y * w1.x + xv.z * w2.x + xv.w * w3.x;
      acc.y += xv.x * w0.y + xv.y * w1.y + xv.z * w2.y + xv.w * w3.y;
      acc.z += xv.x * w0.z + xv.y * w1.z + xv.z * w2.z + xv.w * w3.z;
      acc.w += xv.x * w0.w + xv.y * w1.w + xv.z * w2.w + xv.w * w3.w;
    }
    float di = dinv[r];
    ushort4 o;
    o.x = f2bf(acc.x * di); o.y = f2bf(acc.y * di);
    o.z = f2bf(acc.z * di); o.w = f2bf(acc.w * di);
    *(ushort4*)&supb[(size_t)r * NH + lane16 * 4] = o;
  }
}

// One wave per node: padded segment-reduce with scalar edge loads (uniform j,
// 8 gathers in flight), then LDS-transpose Student-t head.
__global__ __launch_bounds__(256) void k_agg_q(const int2* __restrict__ epair,
                                               const int* __restrict__ off,
                                               const float* __restrict__ dinv,
                                               const u16* __restrict__ supb,
                                               const float* __restrict__ b,
                                               const float* __restrict__ mu,
                                               float* __restrict__ z,
                                               float* __restrict__ q) {
  __shared__ float muL[NK * 68];    // padded rows: stride 68 words breaks bank aliasing
  __shared__ float zsh[4][64];      // one z row per wave
  for (int i = threadIdx.x; i < NK * NH; i += 256) muL[(i >> 6) * 68 + (i & 63)] = mu[i];
  __syncthreads();
  int wid  = (blockIdx.x * 256 + threadIdx.x) >> 6;  // node
  int lane = threadIdx.x & 63;                       // feature
  int wv   = threadIdx.x >> 6;                       // wave in block

  int startU = __builtin_amdgcn_readfirstlane(off[wid]);
  int endU   = __builtin_amdgcn_readfirstlane(off[wid + 1]);
  float di  = dinv[wid];
  float acc0 = bf2f(supb[(size_t)wid * NH + lane]);  // self-loop term
  float acc1 = 0.f;

  for (int j = startU; j < endU; j += 8) {
    int2 e0 = epair[j + 0], e1 = epair[j + 1], e2 = epair[j + 2], e3 = epair[j + 3];
    int2 e4 = epair[j + 4], e5 = epair[j + 5], e6 = epair[j + 6], e7 = epair[j + 7];
    const u16* p0 = supb + ((size_t)e0.x << 6);
    const u16* p1 = supb + ((size_t)e1.x << 6);
    const u16* p2 = supb + ((size_t)e2.x << 6);
    const u16* p3 = supb + ((size_t)e3.x << 6);
    const u16* p4 = supb + ((size_t)e4.x << 6);
    const u16* p5 = supb + ((size_t)e5.x << 6);
    const u16* p6 = supb + ((size_t)e6.x << 6);
    const u16* p7 = supb + ((size_t)e7.x << 6);
    float v0 = bf2f(p0[lane]);
    float v1 = bf2f(p1[lane]);
    float v2 = bf2f(p2[lane]);
    float v3 = bf2f(p3[lane]);
    float v4 = bf2f(p4[lane]);
    float v5 = bf2f(p5[lane]);
    float v6 = bf2f(p6[lane]);
    float v7 = bf2f(p7[lane]);
    acc0 += __int_as_float(e0.y) * v0;
    acc1 += __int_as_float(e1.y) * v1;
    acc0 += __int_as_float(e2.y) * v2;
    acc1 += __int_as_float(e3.y) * v3;
    acc0 += __int_as_float(e4.y) * v4;
    acc1 += __int_as_float(e5.y) * v5;
    acc0 += __int_as_float(e6.y) * v6;
    acc1 += __int_as_float(e7.y) * v7;
  }

  float zz = di * (acc0 + acc1) + b[lane];
  z[(size_t)wid * NH + lane] = zz;
  zsh[wv][lane] = zz;   // same-wave write->read; compiler inserts lgkmcnt wait

  float qv = 0.f;
  if (lane < NK) {
    const float4* zr = (const float4*)zsh[wv];          // broadcast reads
    const float4* mr = (const float4*)&muL[lane * 68];  // per-lane mu row
    float s0 = 0.f, s1 = 0.f, s2 = 0.f, s3 = 0.f;
#pragma unroll
    for (int j = 0; j < 16; ++j) {
      float4 zv = zr[j];
      float4 mv = mr[j];
      float a0 = zv.x - mv.x, a1 = zv.y - mv.y, a2 = zv.z - mv.z, a3 = zv.w - mv.w;
      s0 += a0 * a0; s1 += a1 * a1; s2 += a2 * a2; s3 += a3 * a3;
    }
    float d2 = (s0 + s1) + (s2 + s3);
    float tq = 1.0f / (1.0f + d2 * (1.0f / ALPHA) + 1e-8f);
    qv = exp2f((ALPHA + 1.0f) * __log2f(tq));   // the /2 factor cancels in normalization
  }
  float ssum = qv;
  for (int o = 32; o; o >>= 1) ssum += __shfl_xor(ssum, o, 64);
  if (lane < NK) q[(size_t)wid * NK + lane] = qv / ssum;
}

extern "C" void kernel_launch(void* const* d_in, const int* in_sizes, int n_in,
                              void* d_out, int out_size, void* d_ws, size_t ws_size,
                              hipStream_t stream) {
  const float* x  = (const float*)d_in[0];
  const void*  ei = d_in[1];
  const float* w  = (const float*)d_in[2];
  const float* W  = (const float*)d_in[3];
  const float* b  = (const float*)d_in[4];
  const float* mu = (const float*)d_in[5];

  char* ws = (char*)d_ws;
  int*   flag   = (int*)(ws + O_FLAG);
  float* dinv   = (float*)(ws + O_DINV);
  int*   hist   = (int*)(ws + O_HIST);
  int*   off    = (int*)(ws + O_OFF);
  int*   chs    = (int*)(ws + O_CHS);
  int*   cho    = (int*)(ws + O_CHO);
  int*   gbh    = (int*)(ws + O_GBH);
  int*   bbase  = (int*)(ws + O_BBASE);
  int*   bcur   = (int*)(ws + O_BCUR);
  uint2* coarse = (uint2*)(ws + O_COARSE);
  int2*  epair  = (int2*)(ws + O_EPAIR);
  u16*   supb   = (u16*)(ws + O_SUP);

  float* z = (float*)d_out;
  float* q = (float*)d_out + (size_t)NN * NH;

  hipMemsetAsync(epair, 0, MAXPAIRS * 8, stream);   // zero pads (w=0, src=0)
  hipMemsetAsync(gbh, 0, size_t(NSB) * 4, stream);
  hipLaunchKernelGGL(k_detect,    dim3(1),                   dim3(256), 0, stream, ei, flag);
  hipLaunchKernelGGL(k_bhist,     dim3((NE + CT - 1) / CT),  dim3(256), 0, stream, ei, flag, gbh);
  hipLaunchKernelGGL(k_bscan,     dim3(1),                   dim3(256), 0, stream, gbh, bbase, bcur);
  hipLaunchKernelGGL(k_coarse,    dim3((NE + CT - 1) / CT),  dim3(256), 0, stream, ei, flag, w, bcur, coarse);
  hipLaunchKernelGGL(k_nhist,     dim3(NSB),                 dim3(256), 0, stream, coarse, bbase, hist, dinv);
  hipLaunchKernelGGL(k_chsum,     dim3(NCH),                 dim3(256), 0, stream, hist, chs);
  hipLaunchKernelGGL(k_scantop,   dim3(1),                   dim3(64),  0, stream, chs, cho, off);
  hipLaunchKernelGGL(k_scanapply, dim3(NCH),                 dim3(256), 0, stream, hist, cho, off);
  hipLaunchKernelGGL(k_fine,      dim3(NSB),                 dim3(256), 0, stream, coarse, bbase, off, epair);
  hipLaunchKernelGGL(k_gemm,      dim3((NN + 127) / 128),    dim3(256), 0, stream, x, W, dinv, supb);
  hipLaunchKernelGGL(k_agg_q,     dim3((NN * 64) / 256),     dim3(256), 0, stream, epair, off, dinv, supb, b, mu, z, q);
}